// Round 10
// baseline (43.987 us; speedup 1.0000x reference)
//
#include <hip/hip_runtime.h>

#define BATCH 4096
#define TPTS 512
// RK4 @ h = dt (uniform grid, t = arange). Scaled state p=beta*h*S, q=alpha*h*E, I unscaled.
// J-identity: I1+2I2+2I3+I4 = 6*I + (k1+k2+k3). R/M folded into wb.
// Solo-wave cadence ~4 cyc/instr regardless of ILP (R2/R8/R9); pk ops cost 2 slots (R9 fit).
// This round: 2-step unroll, dual SGPR store bases (one voff bump / 2 steps), step-k out-chain
// interleaved into step-k+1 stage shadow, s_setprio 3 probe.
//
// Register map (all clobbered):
//   v30:31 CPQ2  v32:33 CPQ4  v34:35 CPQ6  v36:37 TWO
//   v40:41 PQ  v42 I  v43 wb  v73 voff
//   v44..51 nd1..nd4  v52..55 k1..k4  v56 I2  v57 I3  v58 I4
//   v60:65 PQ2..PQ4  v66:67 acc  v68..71 t,sk,u,aI  v72 oA  v74 oB

#define CLOB \
    "v30","v31","v32","v33","v34","v35","v36","v37", \
    "v40","v41","v42","v43","v44","v45","v46","v47","v48","v49", \
    "v50","v51","v52","v53","v54","v55","v56","v57","v58", \
    "v60","v61","v62","v63","v64","v65","v66","v67","v68","v69", \
    "v70","v71","v72","v73","v74","memory"

#define ST1 \
    "v_mul_f32 v44, v40, v42\n\t" \
    "v_sub_f32 v45, v44, v41\n\t" \
    "v_fma_f32 v52, %0, v42, v41\n\t" \
    "v_pk_fma_f32 v[60:61], v[30:31], v[44:45], v[40:41]\n\t" \
    "v_fma_f32 v56, 0.5, v52, v42\n\t"
#define ST2 \
    "v_mul_f32 v46, v60, v56\n\t" \
    "v_sub_f32 v47, v46, v61\n\t" \
    "v_fma_f32 v53, %0, v56, v61\n\t" \
    "v_pk_fma_f32 v[62:63], v[30:31], v[46:47], v[40:41]\n\t" \
    "v_fma_f32 v57, 0.5, v53, v42\n\t"
#define ST3 \
    "v_mul_f32 v48, v62, v57\n\t" \
    "v_sub_f32 v49, v48, v63\n\t" \
    "v_fma_f32 v54, %0, v57, v63\n\t" \
    "v_pk_fma_f32 v[64:65], v[32:33], v[48:49], v[40:41]\n\t" \
    "v_add_f32 v58, v54, v42\n\t"
#define ST4 \
    "v_mul_f32 v50, v64, v58\n\t" \
    "v_sub_f32 v51, v50, v65\n\t" \
    "v_fma_f32 v55, %0, v58, v65\n\t"
#define COMB \
    "v_pk_fma_f32 v[66:67], v[36:37], v[46:47], v[44:45]\n\t" \
    "v_pk_fma_f32 v[66:67], v[36:37], v[48:49], v[66:67]\n\t" \
    "v_pk_add_f32 v[66:67], v[66:67], v[50:51]\n\t" \
    "v_add_f32 v68, v53, v54\n\t" \
    "v_add_f32 v69, v52, v68\n\t" \
    "v_add_f32 v70, v69, v68\n\t" \
    "v_add_f32 v71, v70, v55\n\t" \
    "v_fma_f32 v43, %1, v42, v43\n\t" \
    "v_fma_f32 v43, %2, v69, v43\n\t" \
    "v_fma_f32 v42, %3, v71, v42\n\t" \
    "v_pk_fma_f32 v[40:41], v[34:35], v[66:67], v[40:41]\n\t"

#define OUTA1 \
    "v_fma_f32 v72, %4, v42, v43\n\t" \
    "v_fma_f32 v72, %5, v40, v72\n\t"
#define OUTA2 \
    "v_fma_f32 v72, %6, v41, v72\n\t" \
    "global_store_dword v73, v72, %7\n\t"
#define OUTB \
    "v_fma_f32 v74, %4, v42, v43\n\t" \
    "v_fma_f32 v74, %5, v40, v74\n\t" \
    "v_fma_f32 v74, %6, v41, v74\n\t" \
    "global_store_dword v73, v74, %8\n\t" \
    "v_add_u32 v73, 0x8000, v73\n\t"
#define OUTF \
    "v_fma_f32 v72, %4, v42, v43\n\t" \
    "v_fma_f32 v72, %5, v40, v72\n\t" \
    "v_fma_f32 v72, %6, v41, v72\n\t" \
    "global_store_dword v73, v72, %7\n\t"

__global__ __launch_bounds__(64, 1) void seirm_traj_kernel(
    const float* __restrict__ ze_init,  // [1, B, 5]
    const float* __restrict__ tv,       // [T]
    const float* __restrict__ theta,    // [4] beta, alpha, gamma, mu
    const float* __restrict__ Wv,       // [1, 5]
    const float* __restrict__ bv,       // [1]
    float* __restrict__ out)            // [T, B, 1]
{
    const int b = blockIdx.x * 64 + (int)threadIdx.x;

    const float beta  = theta[0];
    const float alpha = theta[1];
    const float gam   = theta[2];
    const float mu    = theta[3];

    const float w0 = Wv[0], w1 = Wv[1], w2 = Wv[2], w3 = Wv[3], w4 = Wv[4];
    const float bias = bv[0];

    const float h  = tv[1] - tv[0];     // uniform grid
    const float bh = beta * h;
    const float ah = alpha * h;
    const float gh = (gam + mu) * h;
    const float ngh = -gh;
    constexpr float SIXTH = 1.0f / 6.0f;

    const float w0p = w0 / bh;
    const float w1p = w1 / ah;
    const float wJ  = fmaf(w3, gam, w4 * mu);
    const float cJ1 = wJ * h;
    const float cJ2 = wJ * h * SIXTH;

    const float S0 = ze_init[b * 5 + 0];
    const float E0 = ze_init[b * 5 + 1];
    const float I0 = ze_init[b * 5 + 2];
    const float R0 = ze_init[b * 5 + 3];
    const float M0 = ze_init[b * 5 + 4];

    const float p0  = bh * S0;
    const float q0  = ah * E0;
    const float wb0 = fmaf(w3, R0, fmaf(w4, M0, bias));

    out[b] = fmaf(w0p, p0, fmaf(w1p, q0, fmaf(w2, I0, wb0)));

    const float* outB2 = out + BATCH;        // second store base (row+1)
    const int voff0 = (b << 2) + BATCH * 4;  // first store -> row 1

    asm volatile(
        "s_setprio 3\n\t"
        "v_mov_b32 v40, %0\n\t"
        "v_mov_b32 v41, %1\n\t"
        "v_mov_b32 v42, %2\n\t"
        "v_mov_b32 v43, %3\n\t"
        "v_mov_b32 v73, %4\n\t"
        "v_mov_b32 v30, %5\n\t"
        "v_mov_b32 v31, %6\n\t"
        "v_mov_b32 v32, %7\n\t"
        "v_mov_b32 v33, %8\n\t"
        "v_mov_b32 v34, %9\n\t"
        "v_mov_b32 v35, %10\n\t"
        "v_mov_b32 v36, 2.0\n\t"
        "v_mov_b32 v37, 2.0\n\t"
        :
        : "v"(p0), "v"(q0), "v"(I0), "v"(wb0), "v"(voff0),
          "v"(-0.5f * bh), "v"(0.5f * ah), "v"(-bh), "v"(ah),
          "v"(-bh * SIXTH), "v"(ah * SIXTH)
        : CLOB);

    // 255 unrolled pairs: rows 1..510. Step-A out-chain interleaved into step-B stage shadow.
    #pragma clang loop unroll(disable)
    for (int i = 0; i < 255; ++i) {
        asm volatile(
            // ---- step A ----
            ST1 ST2 ST3 ST4 COMB
            // ---- step B stages, A-out spliced in ----
            ST1
            OUTA1
            ST2
            OUTA2
            ST3 ST4 COMB
            OUTB
            :
            : "s"(ngh), "s"(cJ1), "s"(cJ2), "s"(SIXTH),
              "s"(w2), "s"(w0p), "s"(w1p), "s"(out), "s"(outB2)
            : CLOB);
    }

    // epilogue: row 511 (voff already points at it)
    asm volatile(
        ST1 ST2 ST3 ST4 COMB
        OUTF
        :
        : "s"(ngh), "s"(cJ1), "s"(cJ2), "s"(SIXTH),
          "s"(w2), "s"(w0p), "s"(w1p), "s"(out), "s"(outB2)
        : CLOB);
}

extern "C" void kernel_launch(void* const* d_in, const int* in_sizes, int n_in,
                              void* d_out, int out_size, void* d_ws, size_t ws_size,
                              hipStream_t stream) {
    const float* ze = (const float*)d_in[0];
    const float* tv = (const float*)d_in[1];
    const float* th = (const float*)d_in[2];
    const float* Wv = (const float*)d_in[3];
    const float* bv = (const float*)d_in[4];
    float* out = (float*)d_out;

    seirm_traj_kernel<<<BATCH / 64, 64, 0, stream>>>(ze, tv, th, Wv, bv, out);
}